// Round 16
// baseline (133.489 us; speedup 1.0000x reference)
//
#include <hip/hip_runtime.h>
#include <stdint.h>

// Swin shifted-window attention, MI355X (gfx950) — round 16.
// PIPELINE x OCCUPANCY (the untested quadrant). The 15-round 2x2: TLP alone
// (r8/r15: 118/121), pipeline alone at 19% occ (r12/r14: 111) — every variant
// maximized one factor of (in-flight bytes/wave) x (resident waves) while
// collapsing the other. This round: depth-2 pipeline where the 2nd in-flight
// set's register cost is cut by staging K via global_load_lds (8KB/wave slot,
// 32KB/block -> LDS allows 5 blocks/CU; r13's mistake was 64KB -> 2 blocks).
// Q+V prefetch direct-to-reg (64 regs); bm at iteration start (L2-hot).
// launch_bounds(256,3): target 3 waves/SIMD = 12 waves/CU WITH pipelining.
// Math/layout/stores = r14/r15 validated; glds roundtrip = r13 validated.

constexpr int WSZ  = 7;
constexpr int NTOK = 49;
constexpr int NH_  = 16;
constexpr int HD_  = 32;
constexpr int SP   = 56;
constexpr int CH   = 512;
constexpr float LOG2E = 1.4426950408889634f;

constexpr int SLOT_BYTES = 8192;                   // K of next wh, per wave
constexpr size_t LDS_BYTES = 4 * SLOT_BYTES;       // 32 KB per 4-wave block

typedef float    f32x4 __attribute__((ext_vector_type(4)));
typedef short    s16x8 __attribute__((ext_vector_type(8)));
typedef _Float16 f16x4 __attribute__((ext_vector_type(4)));

union FragU { uint32_t w[4]; s16x8 v; };

__device__ __forceinline__ uint32_t bf16_hibits(float x) {
    uint32_t u = __float_as_uint(x);
    u += 0x7fffu + ((u >> 16) & 1u);
    return u & 0xffff0000u;
}
__device__ __forceinline__ uint32_t pk_bf16(float a, float b) {
    return (bf16_hibits(a) >> 16) | bf16_hibits(b);
}

// async global->LDS, 16B per lane, dest = uniform base + lane*16
__device__ __forceinline__ void glds16(const float* g, void* l) {
    __builtin_amdgcn_global_load_lds(
        (const __attribute__((address_space(1))) uint32_t*)g,
        (__attribute__((address_space(3))) uint32_t*)l,
        16, 0, 0);
}

// ---------------- pre-kernel: bias+mask matrices (f16) ----------------
// bm[h*4+cls][q][m] (64x64 f16) = (bias+mask)*LOG2E; padding = -1000.
__global__ __launch_bounds__(256)
void build_bm(const float* __restrict__ bias, _Float16* __restrict__ bm)
{
    const int blk = blockIdx.x;          // h*4 + cls
    const int h = blk >> 2, cls = blk & 3;
    for (int idx = threadIdx.x; idx < 4096; idx += 256) {
        const int q = idx >> 6, m = idx & 63;
        float val;
        if (q >= NTOK || m >= NTOK) {
            val = -1000.0f;
        } else {
            const int iq = q / 7, jq = q % 7, im = m / 7, jm = m % 7;
            const int rpi = (iq - im + 6) * 13 + (jq - jm + 6);
            const float bv = bias[rpi * NH_ + h];
            const int rq = ((cls & 2) ? (iq < 4 ? 3 : 6) : 0)
                         + ((cls & 1) ? (jq < 4 ? 1 : 2) : 0);
            const int rm = ((cls & 2) ? (im < 4 ? 3 : 6) : 0)
                         + ((cls & 1) ? (jm < 4 ? 1 : 2) : 0);
            const float mask = (rq != rm) ? -100.0f : 0.0f;
            val = (bv + mask) * LOG2E;
        }
        bm[blk * 4096 + idx] = (_Float16)val;
    }
}

// ---------------- pipeline building blocks ----------------
struct QV { float4 q[4][2]; float v[2][2][8]; };
struct Frag { s16x8 Qh[4], Kh[4], Vb[2][2]; };

__device__ __forceinline__ int make_off(int wh, int lane) {
    const int h  = wh & 15;
    const int w  = wh >> 4;
    const int wc = w & 7, wr = (w >> 3) & 7, b = w >> 6;
    const int t  = lane < NTOK ? lane : NTOK - 1;
    const int it = t / 7, jt = t - 7 * it;
    int sr = wr * 7 + it + 3; if (sr >= SP) sr -= SP;
    int sc = wc * 7 + jt + 3; if (sc >= SP) sc -= SP;
    return ((b * SP + sr) * SP + sc) * CH + h * HD_;
}
__device__ __forceinline__ int cls_of(int wh) {
    const int w = wh >> 4;
    return ((((w >> 3) & 7) == 7) ? 2 : 0) | (((w & 7) == 7) ? 1 : 0);
}

// K of one wh -> wave-private LDS slot (zero VGPR cost, deep vmcnt queue)
__device__ __forceinline__ void glds_K(const float* __restrict__ kg,
                                       int off, int l16, int g, char* slot) {
#pragma unroll
    for (int tt = 0; tt < 4; ++tt) {
        const int o = __shfl(off, 16 * tt + l16);
        const float* kp = kg + o + 8 * g;
        glds16(kp,     slot + (tt * 2 + 0) * 1024);
        glds16(kp + 4, slot + (tt * 2 + 1) * 1024);
    }
}

// Q + V direct-to-register loads; also returns oQK for the O^T stores
__device__ __forceinline__ void issue_qv(const float* __restrict__ qg,
                                         const float* __restrict__ vg,
                                         int off, int l16, int g, QV& r,
                                         int (&oQK)[4]) {
#pragma unroll
    for (int tt = 0; tt < 4; ++tt) oQK[tt] = __shfl(off, 16 * tt + l16);
    int oV[16];
#pragma unroll
    for (int mc = 0; mc < 2; ++mc)
#pragma unroll
        for (int e = 0; e < 8; ++e) oV[8 * mc + e] = __shfl(off, 32 * mc + 8 * g + e);
#pragma unroll
    for (int tt = 0; tt < 4; ++tt) {
        const float* qp = qg + oQK[tt] + 8 * g;
        r.q[tt][0] = *(const float4*)qp;  r.q[tt][1] = *(const float4*)(qp + 4);
    }
#pragma unroll
    for (int mc = 0; mc < 2; ++mc)
#pragma unroll
        for (int dh = 0; dh < 2; ++dh)
#pragma unroll
            for (int e = 0; e < 8; ++e)
                r.v[mc][dh][e] = vg[oV[8 * mc + e] + 16 * dh + l16];
}

// LDS K readback (identity: lane reads its own 16B) + convert everything
__device__ __forceinline__ void convert_all(const char* slot, const QV& r,
                                            float qs, int lane, Frag& f) {
#pragma unroll
    for (int tt = 0; tt < 4; ++tt) {
        const float4 k0 = *(const float4*)(slot + (tt * 2 + 0) * 1024 + lane * 16);
        const float4 k1 = *(const float4*)(slot + (tt * 2 + 1) * 1024 + lane * 16);
        FragU qh, kh;
        qh.w[0] = pk_bf16(r.q[tt][0].x * qs, r.q[tt][0].y * qs);
        qh.w[1] = pk_bf16(r.q[tt][0].z * qs, r.q[tt][0].w * qs);
        qh.w[2] = pk_bf16(r.q[tt][1].x * qs, r.q[tt][1].y * qs);
        qh.w[3] = pk_bf16(r.q[tt][1].z * qs, r.q[tt][1].w * qs);
        kh.w[0] = pk_bf16(k0.x, k0.y);
        kh.w[1] = pk_bf16(k0.z, k0.w);
        kh.w[2] = pk_bf16(k1.x, k1.y);
        kh.w[3] = pk_bf16(k1.z, k1.w);
        f.Qh[tt] = qh.v; f.Kh[tt] = kh.v;
    }
#pragma unroll
    for (int mc = 0; mc < 2; ++mc)
#pragma unroll
        for (int dh = 0; dh < 2; ++dh) {
            FragU fu;
#pragma unroll
            for (int wd = 0; wd < 4; ++wd)
                fu.w[wd] = pk_bf16(r.v[mc][dh][2 * wd], r.v[mc][dh][2 * wd + 1]);
            f.Vb[mc][dh] = fu.v;
        }
}

__device__ __forceinline__ void load_bm(const _Float16* __restrict__ bmh,
                                        int l16, int g, f16x4 (&bmr)[4][4]) {
#pragma unroll
    for (int tq = 0; tq < 4; ++tq)
#pragma unroll
        for (int tk = 0; tk < 4; ++tk)
            bmr[tq][tk] = *(const f16x4*)(bmh + (16 * tq + l16) * 64 + 16 * tk + 4 * g);
}

__device__ __forceinline__ void do_math(const Frag& f, const f16x4 (&bmr)[4][4],
                                        const int (&oQK)[4], int lane, int g, int l16,
                                        float* __restrict__ outg) {
    // S^T = K·Q^T tiles, fused exp2 + bf16 pack + denom
    uint32_t u0[4][4], u1[4][4];
    float inv[4];
#pragma unroll
    for (int tq = 0; tq < 4; ++tq) {
        float dsum = 0.f;
#pragma unroll
        for (int tk = 0; tk < 4; ++tk) {
            f32x4 a;
            a[0] = (float)bmr[tq][tk][0] - 23.f;
            a[1] = (float)bmr[tq][tk][1] - 23.f;
            a[2] = (float)bmr[tq][tk][2] - 23.f;
            a[3] = (float)bmr[tq][tk][3] - 23.f;
            a = __builtin_amdgcn_mfma_f32_16x16x32_bf16(f.Kh[tk], f.Qh[tq], a, 0, 0, 0);
            float e0 = __builtin_amdgcn_exp2f(a[0]);
            float e1 = __builtin_amdgcn_exp2f(a[1]);
            float e2 = __builtin_amdgcn_exp2f(a[2]);
            float e3 = __builtin_amdgcn_exp2f(a[3]);
            dsum += (e0 + e1) + (e2 + e3);
            u0[tq][tk] = pk_bf16(e0, e1);
            u1[tq][tk] = pk_bf16(e2, e3);
        }
        dsum += __shfl_xor(dsum, 16);
        dsum += __shfl_xor(dsum, 32);
        inv[tq] = 1.0f / (dsum + 1e-30f);   // lane-local for q = 16tq + l16
    }

    // repack P (C-layout) -> fragments (r10-validated mapping)
    const int srcb = 32 * (g & 1) + l16;
    const bool hiG = (lane >= 32);
    s16x8 PA[4][2];
#pragma unroll
    for (int tq = 0; tq < 4; ++tq)
#pragma unroll
        for (int mc = 0; mc < 2; ++mc) {
            FragU fu;
#pragma unroll
            for (int wd = 0; wd < 4; ++wd) {
                const int sl = srcb + 16 * (wd >> 1);
                uint32_t A, B;
                if (wd & 1) {
                    A = __shfl(u1[tq][2 * mc],     sl);
                    B = __shfl(u1[tq][2 * mc + 1], sl);
                } else {
                    A = __shfl(u0[tq][2 * mc],     sl);
                    B = __shfl(u0[tq][2 * mc + 1], sl);
                }
                fu.w[wd] = hiG ? B : A;
            }
            PA[tq][mc] = fu.v;
        }

    // O^T = V^T·P^T: mfma(A=Vb, B=PA) -> C[d][q] (r14-validated)
#pragma unroll
    for (int tq = 0; tq < 4; ++tq) {
        const float iv = inv[tq];
        const bool ok = (tq < 3) || (l16 == 0);     // token 16tq+l16 < 49
#pragma unroll
        for (int dh = 0; dh < 2; ++dh) {
            f32x4 a = {0.f, 0.f, 0.f, 0.f};
            a = __builtin_amdgcn_mfma_f32_16x16x32_bf16(f.Vb[0][dh], PA[tq][0], a, 0, 0, 0);
            a = __builtin_amdgcn_mfma_f32_16x16x32_bf16(f.Vb[1][dh], PA[tq][1], a, 0, 0, 0);
            if (ok) {
                float4 st;
                st.x = a[0] * iv; st.y = a[1] * iv;
                st.z = a[2] * iv; st.w = a[3] * iv;
                *(float4*)(outg + oQK[tq] + 16 * dh + 4 * g) = st;
            }
        }
    }
}

__device__ __forceinline__ void wait_vmem() {
    asm volatile("s_waitcnt vmcnt(0)" ::: "memory");
    __builtin_amdgcn_sched_barrier(0);
}
__device__ __forceinline__ void drain_lds() {
    asm volatile("s_waitcnt lgkmcnt(0)" ::: "memory");
    __builtin_amdgcn_sched_barrier(0);
}

// ---------------- main depth-2 pipelined kernel ----------------
__global__ __launch_bounds__(256, 3)
void swin_d2_kernel(const float* __restrict__ qg,
                    const float* __restrict__ kg,
                    const float* __restrict__ vg,
                    const _Float16* __restrict__ bm,
                    float* __restrict__ outg)
{
    extern __shared__ char smem[];
    const int wave = threadIdx.x >> 6;
    char* slot = smem + wave * SLOT_BYTES;      // wave-private: no syncthreads
    const int gw   = blockIdx.x * 4 + wave;     // 0..8191
    const int lane = threadIdx.x & 63;
    const int g    = lane >> 4;
    const int l16  = lane & 15;
    const float qs = 0.17677669529663687f * LOG2E;

    const int h = gw & 15;                       // same head for both whs
    const _Float16* bmhead = bm + (size_t)h * 4 * 4096;

    const int wh0 = gw, wh1 = gw + 8192;
    QV r0, r1;
    Frag f;
    f16x4 bmr[4][4];
    int oQK0[4], oQK1[4];

    const int off0 = make_off(wh0, lane);
    glds_K(kg, off0, l16, g, slot);
    issue_qv(qg, vg, off0, l16, g, r0, oQK0);

    // ---- iteration 0: consume wh0, prefetch wh1 during math ----
    wait_vmem();                                  // K0 in LDS, Q0/V0 in regs
    convert_all(slot, r0, qs, lane, f);
    drain_lds();                                  // slot reads done before reuse
    const int off1 = make_off(wh1, lane);
    glds_K(kg, off1, l16, g, slot);               // in flight during math0
    issue_qv(qg, vg, off1, l16, g, r1, oQK1);     // in flight during math0
    load_bm(bmhead + cls_of(wh0) * 4096, l16, g, bmr);
    __builtin_amdgcn_sched_barrier(0);
    do_math(f, bmr, oQK0, lane, g, l16, outg);

    // ---- iteration 1: consume wh1 ----
    wait_vmem();
    convert_all(slot, r1, qs, lane, f);
    load_bm(bmhead + cls_of(wh1) * 4096, l16, g, bmr);
    __builtin_amdgcn_sched_barrier(0);
    do_math(f, bmr, oQK1, lane, g, l16, outg);
}

// ---------------- fallback scalar kernel (round-3) ----------------
__global__ __launch_bounds__(256)
void swin_block_scalar(const float* __restrict__ qg,
                       const float* __restrict__ kg,
                       const float* __restrict__ vg,
                       const float* __restrict__ bias,
                       float* __restrict__ outg)
{
    const int wave = __builtin_amdgcn_readfirstlane(threadIdx.x >> 6);
    const int wh   = blockIdx.x * 4 + wave;
    const int h    = wh & (NH_ - 1);
    const int w    = wh >> 4;
    const int wc   = w & 7;
    const int wr   = (w >> 3) & 7;
    const int b    = w >> 6;

    const int lane = threadIdx.x & 63;
    const int rr   = lane < NTOK ? lane : NTOK - 1;
    const int i    = rr / WSZ;
    const int j    = rr - i * WSZ;

    const int hp = wr * WSZ + i;
    const int wp = wc * WSZ + j;
    int sr = hp + 3; if (sr >= SP) sr -= SP;
    int sc = wp + 3; if (sc >= SP) sc -= SP;
    const int rowoff = ((b * SP + sr) * SP + sc) * CH + h * HD_;
    const int reg_r = (hp < 49 ? 0 : (hp < 53 ? 3 : 6))
                    + (wp < 49 ? 0 : (wp < 53 ? 1 : 2));
    const float qscale = 0.17677669529663687f * LOG2E;

    float qr[HD_];
    {
        const float4* qp = reinterpret_cast<const float4*>(qg + rowoff);
#pragma unroll
        for (int tt = 0; tt < HD_ / 4; ++tt) {
            float4 x = qp[tt];
            qr[4*tt+0] = x.x * qscale; qr[4*tt+1] = x.y * qscale;
            qr[4*tt+2] = x.z * qscale; qr[4*tt+3] = x.w * qscale;
        }
    }
    const int biaslane = (i * 13 + j) * 16 + h;
    float o[HD_];
#pragma unroll
    for (int d = 0; d < HD_; ++d) o[d] = 0.f;
    float denom = 0.f;
    const float* kb = kg + b * SP * SP * CH + h * HD_;
    const float* vb = vg + b * SP * SP * CH + h * HD_;

    for (int ic = 0; ic < WSZ; ++ic) {
        const int hpc = wr * WSZ + ic;
        int src_r = hpc + 3; if (src_r >= SP) src_r -= SP;
        const int regh_c = (hpc < 49 ? 0 : (hpc < 53 ? 3 : 6));
        const float* krow0 = kb + src_r * SP * CH;
        const float* vrow0 = vb + src_r * SP * CH;
        float e[WSZ];
#pragma unroll
        for (int u = 0; u < WSZ; ++u) {
            const int wpc = wc * WSZ + u;
            int src_c = wpc + 3; if (src_c >= SP) src_c -= SP;
            const int reg_c = regh_c + (wpc < 49 ? 0 : (wpc < 53 ? 1 : 2));
            const float* krow = krow0 + src_c * CH;
            const float bv = bias[biaslane + ((6 - ic) * 13 + (6 - u)) * 16];
            float s0 = fmaf(bv, LOG2E, (reg_r != reg_c) ? -167.26950408889634f : -23.0f);
            float s1 = 0.f, s2 = 0.f, s3 = 0.f;
#pragma unroll
            for (int d = 0; d < HD_; d += 4) {
                s0 = fmaf(qr[d+0], krow[d+0], s0);
                s1 = fmaf(qr[d+1], krow[d+1], s1);
                s2 = fmaf(qr[d+2], krow[d+2], s2);
                s3 = fmaf(qr[d+3], krow[d+3], s3);
            }
            e[u] = exp2f((s0 + s1) + (s2 + s3));
            denom += e[u];
        }
#pragma unroll
        for (int u = 0; u < WSZ; ++u) {
            const int wpc = wc * WSZ + u;
            int src_c = wpc + 3; if (src_c >= SP) src_c -= SP;
            const float* vrow = vrow0 + src_c * CH;
            const float ev = e[u];
#pragma unroll
            for (int d = 0; d < HD_; ++d) o[d] = fmaf(ev, vrow[d], o[d]);
        }
    }
    const float invd = 1.0f / denom;
    if (lane < NTOK) {
        float4* op = reinterpret_cast<float4*>(outg + rowoff);
#pragma unroll
        for (int tt = 0; tt < HD_ / 4; ++tt) {
            float4 x;
            x.x = o[4*tt+0] * invd; x.y = o[4*tt+1] * invd;
            x.z = o[4*tt+2] * invd; x.w = o[4*tt+3] * invd;
            op[tt] = x;
        }
    }
}

extern "C" void kernel_launch(void* const* d_in, const int* in_sizes, int n_in,
                              void* d_out, int out_size, void* d_ws, size_t ws_size,
                              hipStream_t stream) {
    const float* q    = (const float*)d_in[0];
    const float* k    = (const float*)d_in[1];
    const float* v    = (const float*)d_in[2];
    const float* bias = (const float*)d_in[3];
    float* out        = (float*)d_out;

    const int B   = in_sizes[0] / (SP * SP * CH);
    const int nwh = B * (SP / WSZ) * (SP / WSZ) * NH_;   // 16384

    const size_t bm_bytes = (size_t)NH_ * 4 * 4096 * sizeof(_Float16);  // 512 KB
    if (ws_size >= bm_bytes) {
        _Float16* bm = (_Float16*)d_ws;
        hipLaunchKernelGGL(build_bm, dim3(NH_ * 4), dim3(256), 0, stream, bias, bm);
        // depth-2: nwh/2 waves = nwh/8 blocks = 2048
        hipLaunchKernelGGL(swin_d2_kernel, dim3(nwh / 8), dim3(256), LDS_BYTES,
                           stream, q, k, v, bm, out);
    } else {
        hipLaunchKernelGGL(swin_block_scalar, dim3(nwh / 4), dim3(256), 0, stream,
                           q, k, v, bias, out);
    }
}

// Round 17
// 101.700 us; speedup vs baseline: 1.3126x; 1.3126x over previous
//
#include <hip/hip_runtime.h>
#include <stdint.h>

// Swin shifted-window attention, MI355X (gfx950) — round 17.
// FORCED MLP VIA INLINE-ASM LOADS. r8/r10/r12/r16 all tried to hold a full
// 48-load set in registers and the compiler defeated every one (re-roll to
// VGPR 60/84/128, or r16's scratch spill: WRITE_SIZE 100->129MB). Inline asm
// with "=&v" outputs is opaque to the scheduler/allocator: all 48 Q/K/V loads
// issue back-to-back into distinct registers, one s_waitcnt vmcnt(0) +
// sched_barrier(0) fence (compiler does NOT track asm loads - manual fence is
// mandatory), then the r15-validated math. offset: immediates reuse address
// registers for the second half of each pair. launch_bounds(256,2).
// Observable: VGPR_Count >= ~160 proves the mechanism engaged.

constexpr int WSZ  = 7;
constexpr int NTOK = 49;
constexpr int NH_  = 16;
constexpr int HD_  = 32;
constexpr int SP   = 56;
constexpr int CH   = 512;
constexpr float LOG2E = 1.4426950408889634f;

typedef float    f32x4 __attribute__((ext_vector_type(4)));
typedef short    s16x8 __attribute__((ext_vector_type(8)));
typedef _Float16 f16x4 __attribute__((ext_vector_type(4)));

union FragU { uint32_t w[4]; s16x8 v; };

__device__ __forceinline__ uint32_t bf16_hibits(float x) {
    uint32_t u = __float_as_uint(x);
    u += 0x7fffu + ((u >> 16) & 1u);
    return u & 0xffff0000u;
}
__device__ __forceinline__ uint32_t pk_bf16(float a, float b) {
    return (bf16_hibits(a) >> 16) | bf16_hibits(b);
}

// ---- inline-asm loads: results pinned in distinct VGPRs, issue-ordered ----
// two dwordx4 from one address (second at +16B) — early-clobber so dests
// can never alias the address pair while loads are in flight.
__device__ __forceinline__ void ld128x2(const float* p, float4& lo, float4& hi) {
    asm volatile("global_load_dwordx4 %0, %2, off\n\t"
                 "global_load_dwordx4 %1, %2, off offset:16"
                 : "=&v"(lo), "=&v"(hi) : "v"(p) : "memory");
}
// two dwords from one address (second at +64B = 16 floats)
__device__ __forceinline__ void ld32x2(const float* p, float& a, float& b) {
    asm volatile("global_load_dword %0, %2, off\n\t"
                 "global_load_dword %1, %2, off offset:64"
                 : "=&v"(a), "=&v"(b) : "v"(p) : "memory");
}
__device__ __forceinline__ void fence_vmem() {
    asm volatile("s_waitcnt vmcnt(0)" ::: "memory");
    __builtin_amdgcn_sched_barrier(0);
}

// ---------------- pre-kernel: bias+mask matrices (f16) ----------------
// bm[h*4+cls][q][m] (64x64 f16) = (bias+mask)*LOG2E; padding = -1000.
__global__ __launch_bounds__(256)
void build_bm(const float* __restrict__ bias, _Float16* __restrict__ bm)
{
    const int blk = blockIdx.x;          // h*4 + cls
    const int h = blk >> 2, cls = blk & 3;
    for (int idx = threadIdx.x; idx < 4096; idx += 256) {
        const int q = idx >> 6, m = idx & 63;
        float val;
        if (q >= NTOK || m >= NTOK) {
            val = -1000.0f;
        } else {
            const int iq = q / 7, jq = q % 7, im = m / 7, jm = m % 7;
            const int rpi = (iq - im + 6) * 13 + (jq - jm + 6);
            const float bv = bias[rpi * NH_ + h];
            const int rq = ((cls & 2) ? (iq < 4 ? 3 : 6) : 0)
                         + ((cls & 1) ? (jq < 4 ? 1 : 2) : 0);
            const int rm = ((cls & 2) ? (im < 4 ? 3 : 6) : 0)
                         + ((cls & 1) ? (jm < 4 ? 1 : 2) : 0);
            const float mask = (rq != rm) ? -100.0f : 0.0f;
            val = (bv + mask) * LOG2E;
        }
        bm[blk * 4096 + idx] = (_Float16)val;
    }
}

// ---------------- main MFMA kernel: one wh per wave, forced MLP ----------------
__global__ __launch_bounds__(256, 2)
void swin_mfma_kernel(const float* __restrict__ qg,
                      const float* __restrict__ kg,
                      const float* __restrict__ vg,
                      const _Float16* __restrict__ bm,
                      float* __restrict__ outg)
{
    const int wave = threadIdx.x >> 6;
    const int wh   = blockIdx.x * 4 + wave;
    const int h    = wh & (NH_ - 1);
    const int w    = wh >> 4;
    const int wc   = w & 7;
    const int wr   = (w >> 3) & 7;
    const int b    = w >> 6;

    const int lane = threadIdx.x & 63;
    const int g    = lane >> 4;
    const int l16  = lane & 15;

    // per-lane token offset (token = lane, clamped to 48)
    const int t  = lane < NTOK ? lane : NTOK - 1;
    const int it = t / 7, jt = t - 7 * it;
    int sr = wr * 7 + it + 3; if (sr >= SP) sr -= SP;
    int sc = wc * 7 + jt + 3; if (sc >= SP) sc -= SP;
    const int off_t = ((b * SP + sr) * SP + sc) * CH + h * HD_;

    // ---- all addresses ----
    int oQK[4];
#pragma unroll
    for (int tt = 0; tt < 4; ++tt) oQK[tt] = __shfl(off_t, 16 * tt + l16);
    int oV[16];
#pragma unroll
    for (int mc = 0; mc < 2; ++mc)
#pragma unroll
        for (int e = 0; e < 8; ++e) oV[8 * mc + e] = __shfl(off_t, 32 * mc + 8 * g + e);

    const int cls = ((wr == 7) ? 2 : 0) | ((wc == 7) ? 1 : 0);
    const _Float16* bmh = bm + ((size_t)h * 4 + cls) * 4096;

    // ---- issue ALL 48 loads back-to-back via inline asm (un-defeatable) ----
    float4 qa[4][2], ka[4][2];
#pragma unroll
    for (int tt = 0; tt < 4; ++tt)
        ld128x2(qg + oQK[tt] + 8 * g, qa[tt][0], qa[tt][1]);
#pragma unroll
    for (int tt = 0; tt < 4; ++tt)
        ld128x2(kg + oQK[tt] + 8 * g, ka[tt][0], ka[tt][1]);
    float va[2][2][8];
#pragma unroll
    for (int mc = 0; mc < 2; ++mc)
#pragma unroll
        for (int e = 0; e < 8; ++e)
            ld32x2(vg + oV[8 * mc + e] + l16, va[mc][0][e], va[mc][1][e]);

    // bm fragments (L2-hot) — normal loads, join the in-flight queue
    f16x4 bmr[4][4];
#pragma unroll
    for (int tq = 0; tq < 4; ++tq)
#pragma unroll
        for (int tk = 0; tk < 4; ++tk)
            bmr[tq][tk] = *(const f16x4*)(bmh + (16 * tq + l16) * 64 + 16 * tk + 4 * g);

    // single drain + scheduling fence (compiler does not track asm loads)
    fence_vmem();

    const float qs = 0.17677669529663687f * LOG2E;  // (1/sqrt(32))*log2(e)

    // ---- converts (Q pre-scaled bf16, K bf16, V bf16) ----
    s16x8 Qh[4], Kh[4], Vb[2][2];
#pragma unroll
    for (int tt = 0; tt < 4; ++tt) {
        FragU qh, kh;
        qh.w[0] = pk_bf16(qa[tt][0].x * qs, qa[tt][0].y * qs);
        qh.w[1] = pk_bf16(qa[tt][0].z * qs, qa[tt][0].w * qs);
        qh.w[2] = pk_bf16(qa[tt][1].x * qs, qa[tt][1].y * qs);
        qh.w[3] = pk_bf16(qa[tt][1].z * qs, qa[tt][1].w * qs);
        kh.w[0] = pk_bf16(ka[tt][0].x, ka[tt][0].y);
        kh.w[1] = pk_bf16(ka[tt][0].z, ka[tt][0].w);
        kh.w[2] = pk_bf16(ka[tt][1].x, ka[tt][1].y);
        kh.w[3] = pk_bf16(ka[tt][1].z, ka[tt][1].w);
        Qh[tt] = qh.v; Kh[tt] = kh.v;
    }
#pragma unroll
    for (int mc = 0; mc < 2; ++mc)
#pragma unroll
        for (int dh = 0; dh < 2; ++dh) {
            FragU fu;
#pragma unroll
            for (int wd = 0; wd < 4; ++wd)
                fu.w[wd] = pk_bf16(va[mc][dh][2 * wd], va[mc][dh][2 * wd + 1]);
            Vb[mc][dh] = fu.v;
        }

    // ---- S^T = K·Q^T tiles, fused exp2 + bf16 pack + denom ----
    uint32_t u0[4][4], u1[4][4];
    float inv[4];
#pragma unroll
    for (int tq = 0; tq < 4; ++tq) {
        float dsum = 0.f;
#pragma unroll
        for (int tk = 0; tk < 4; ++tk) {
            f32x4 a;
            a[0] = (float)bmr[tq][tk][0] - 23.f;
            a[1] = (float)bmr[tq][tk][1] - 23.f;
            a[2] = (float)bmr[tq][tk][2] - 23.f;
            a[3] = (float)bmr[tq][tk][3] - 23.f;
            a = __builtin_amdgcn_mfma_f32_16x16x32_bf16(Kh[tk], Qh[tq], a, 0, 0, 0);
            float e0 = __builtin_amdgcn_exp2f(a[0]);
            float e1 = __builtin_amdgcn_exp2f(a[1]);
            float e2 = __builtin_amdgcn_exp2f(a[2]);
            float e3 = __builtin_amdgcn_exp2f(a[3]);
            dsum += (e0 + e1) + (e2 + e3);
            u0[tq][tk] = pk_bf16(e0, e1);
            u1[tq][tk] = pk_bf16(e2, e3);
        }
        dsum += __shfl_xor(dsum, 16);
        dsum += __shfl_xor(dsum, 32);
        inv[tq] = 1.0f / (dsum + 1e-30f);   // lane-local for q = 16tq + l16
    }

    // ---- repack P (C-layout) -> fragments (r10-validated mapping) ----
    const int srcb = 32 * (g & 1) + l16;
    const bool hiG = (lane >= 32);
    s16x8 PA[4][2];
#pragma unroll
    for (int tq = 0; tq < 4; ++tq)
#pragma unroll
        for (int mc = 0; mc < 2; ++mc) {
            FragU fu;
#pragma unroll
            for (int wd = 0; wd < 4; ++wd) {
                const int sl = srcb + 16 * (wd >> 1);
                uint32_t A, B;
                if (wd & 1) {
                    A = __shfl(u1[tq][2 * mc],     sl);
                    B = __shfl(u1[tq][2 * mc + 1], sl);
                } else {
                    A = __shfl(u0[tq][2 * mc],     sl);
                    B = __shfl(u0[tq][2 * mc + 1], sl);
                }
                fu.w[wd] = hiG ? B : A;
            }
            PA[tq][mc] = fu.v;
        }

    // ---- O^T = V^T·P^T: mfma(A=Vb, B=PA) -> C[d][q] (r14-validated) ----
    // C-layout: col = l16 = q (tile tq), row = 4g+r = d (within 16dh).
    // Store: lane-local float4 at oQK[tq] + 16dh + 4g; iv lane-local.
#pragma unroll
    for (int tq = 0; tq < 4; ++tq) {
        const float iv = inv[tq];
        const bool ok = (tq < 3) || (l16 == 0);     // token 16tq+l16 < 49
#pragma unroll
        for (int dh = 0; dh < 2; ++dh) {
            f32x4 a = {0.f, 0.f, 0.f, 0.f};
            a = __builtin_amdgcn_mfma_f32_16x16x32_bf16(Vb[0][dh], PA[tq][0], a, 0, 0, 0);
            a = __builtin_amdgcn_mfma_f32_16x16x32_bf16(Vb[1][dh], PA[tq][1], a, 0, 0, 0);
            if (ok) {
                float4 st;
                st.x = a[0] * iv; st.y = a[1] * iv;
                st.z = a[2] * iv; st.w = a[3] * iv;
                *(float4*)(outg + oQK[tq] + 16 * dh + 4 * g) = st;
            }
        }
    }
}

// ---------------- fallback scalar kernel (round-3) ----------------
__global__ __launch_bounds__(256)
void swin_block_scalar(const float* __restrict__ qg,
                       const float* __restrict__ kg,
                       const float* __restrict__ vg,
                       const float* __restrict__ bias,
                       float* __restrict__ outg)
{
    const int wave = __builtin_amdgcn_readfirstlane(threadIdx.x >> 6);
    const int wh   = blockIdx.x * 4 + wave;
    const int h    = wh & (NH_ - 1);
    const int w    = wh >> 4;
    const int wc   = w & 7;
    const int wr   = (w >> 3) & 7;
    const int b    = w >> 6;

    const int lane = threadIdx.x & 63;
    const int rr   = lane < NTOK ? lane : NTOK - 1;
    const int i    = rr / WSZ;
    const int j    = rr - i * WSZ;

    const int hp = wr * WSZ + i;
    const int wp = wc * WSZ + j;
    int sr = hp + 3; if (sr >= SP) sr -= SP;
    int sc = wp + 3; if (sc >= SP) sc -= SP;
    const int rowoff = ((b * SP + sr) * SP + sc) * CH + h * HD_;
    const int reg_r = (hp < 49 ? 0 : (hp < 53 ? 3 : 6))
                    + (wp < 49 ? 0 : (wp < 53 ? 1 : 2));
    const float qscale = 0.17677669529663687f * LOG2E;

    float qr[HD_];
    {
        const float4* qp = reinterpret_cast<const float4*>(qg + rowoff);
#pragma unroll
        for (int tt = 0; tt < HD_ / 4; ++tt) {
            float4 x = qp[tt];
            qr[4*tt+0] = x.x * qscale; qr[4*tt+1] = x.y * qscale;
            qr[4*tt+2] = x.z * qscale; qr[4*tt+3] = x.w * qscale;
        }
    }
    const int biaslane = (i * 13 + j) * 16 + h;
    float o[HD_];
#pragma unroll
    for (int d = 0; d < HD_; ++d) o[d] = 0.f;
    float denom = 0.f;
    const float* kb = kg + b * SP * SP * CH + h * HD_;
    const float* vb = vg + b * SP * SP * CH + h * HD_;

    for (int ic = 0; ic < WSZ; ++ic) {
        const int hpc = wr * WSZ + ic;
        int src_r = hpc + 3; if (src_r >= SP) src_r -= SP;
        const int regh_c = (hpc < 49 ? 0 : (hpc < 53 ? 3 : 6));
        const float* krow0 = kb + src_r * SP * CH;
        const float* vrow0 = vb + src_r * SP * CH;
        float e[WSZ];
#pragma unroll
        for (int u = 0; u < WSZ; ++u) {
            const int wpc = wc * WSZ + u;
            int src_c = wpc + 3; if (src_c >= SP) src_c -= SP;
            const int reg_c = regh_c + (wpc < 49 ? 0 : (wpc < 53 ? 1 : 2));
            const float* krow = krow0 + src_c * CH;
            const float bv = bias[biaslane + ((6 - ic) * 13 + (6 - u)) * 16];
            float s0 = fmaf(bv, LOG2E, (reg_r != reg_c) ? -167.26950408889634f : -23.0f);
            float s1 = 0.f, s2 = 0.f, s3 = 0.f;
#pragma unroll
            for (int d = 0; d < HD_; d += 4) {
                s0 = fmaf(qr[d+0], krow[d+0], s0);
                s1 = fmaf(qr[d+1], krow[d+1], s1);
                s2 = fmaf(qr[d+2], krow[d+2], s2);
                s3 = fmaf(qr[d+3], krow[d+3], s3);
            }
            e[u] = exp2f((s0 + s1) + (s2 + s3));
            denom += e[u];
        }
#pragma unroll
        for (int u = 0; u < WSZ; ++u) {
            const int wpc = wc * WSZ + u;
            int src_c = wpc + 3; if (src_c >= SP) src_c -= SP;
            const float* vrow = vrow0 + src_c * CH;
            const float ev = e[u];
#pragma unroll
            for (int d = 0; d < HD_; ++d) o[d] = fmaf(ev, vrow[d], o[d]);
        }
    }
    const float invd = 1.0f / denom;
    if (lane < NTOK) {
        float4* op = reinterpret_cast<float4*>(outg + rowoff);
#pragma unroll
        for (int tt = 0; tt < HD_ / 4; ++tt) {
            float4 x;
            x.x = o[4*tt+0] * invd; x.y = o[4*tt+1] * invd;
            x.z = o[4*tt+2] * invd; x.w = o[4*tt+3] * invd;
            op[tt] = x;
        }
    }
}

extern "C" void kernel_launch(void* const* d_in, const int* in_sizes, int n_in,
                              void* d_out, int out_size, void* d_ws, size_t ws_size,
                              hipStream_t stream) {
    const float* q    = (const float*)d_in[0];
    const float* k    = (const float*)d_in[1];
    const float* v    = (const float*)d_in[2];
    const float* bias = (const float*)d_in[3];
    float* out        = (float*)d_out;

    const int B   = in_sizes[0] / (SP * SP * CH);
    const int nwh = B * (SP / WSZ) * (SP / WSZ) * NH_;   // 16384

    const size_t bm_bytes = (size_t)NH_ * 4 * 4096 * sizeof(_Float16);  // 512 KB
    if (ws_size >= bm_bytes) {
        _Float16* bm = (_Float16*)d_ws;
        hipLaunchKernelGGL(build_bm, dim3(NH_ * 4), dim3(256), 0, stream, bias, bm);
        // one wh per wave, 4 waves per block -> nwh/4 = 4096 blocks
        hipLaunchKernelGGL(swin_mfma_kernel, dim3(nwh / 4), dim3(256), 0, stream,
                           q, k, v, bm, out);
    } else {
        hipLaunchKernelGGL(swin_block_scalar, dim3(nwh / 4), dim3(256), 0, stream,
                           q, k, v, bias, out);
    }
}